// Round 2
// baseline (3971.597 us; speedup 1.0000x reference)
//
#include <hip/hip_runtime.h>
#include <hip/hip_bf16.h>
#include <math.h>

#define N_NODES 50000
#define N_EDGES 800000
#define HID 128
#define NF 128
#define C3 384   // 3*H
#define SILU_SCALE (1.0f/0.6f)
#define INV_SQRT3 0.57735026918962576f
#define INV_SQRTH 0.08838834764831845f   // 1/sqrt(128)

typedef __bf16 bf16x8 __attribute__((ext_vector_type(8)));
typedef __bf16 bf16x4 __attribute__((ext_vector_type(4)));
typedef float  floatx4 __attribute__((ext_vector_type(4)));

// ---------------------------------------------------------------------------
// Cast + transpose We [128][384] f32 -> WeT [384][128] bf16 (B-operand layout)
// ---------------------------------------------------------------------------
__global__ void cast_weT(const float* __restrict__ We, __bf16* __restrict__ WeT) {
    int o = blockIdx.x * 256 + threadIdx.x;   // 49152 total
    int n = o / NF, k = o % NF;
    WeT[o] = (__bf16)We[k * C3 + n];
}

// ---------------------------------------------------------------------------
// Node MLP: 16 nodes per block of 384 threads (unchanged from verified v1).
// ---------------------------------------------------------------------------
__global__ __launch_bounds__(384)
void node_mlp(const float* __restrict__ x,  const float* __restrict__ W1,
              const float* __restrict__ b1, const float* __restrict__ W2,
              const float* __restrict__ b2, float* __restrict__ x_h) {
    __shared__ float xs[16][HID];   // 8 KB
    __shared__ float hs[16][64];    // 4 KB
    const int t = threadIdx.x;
    const int base = blockIdx.x * 16;

    for (int f4 = t; f4 < 512; f4 += 384) {   // 16*128 floats = 512 float4
        float4 v = ((const float4*)(x + (size_t)base * HID))[f4];
        ((float4*)&xs[0][0])[f4] = v;
    }
    __syncthreads();
    for (int o = t; o < 1024; o += 384) {     // 16 nodes x 64 mid
        int g = o >> 6, m = o & 63;
        float sum = b1[m];
        #pragma unroll 8
        for (int k = 0; k < HID; ++k) sum += xs[g][k] * W1[k * 64 + m];
        float sig = 1.0f / (1.0f + __expf(-sum));
        hs[g][m] = sum * sig * SILU_SCALE;
    }
    __syncthreads();
    {
        float acc[16];
        #pragma unroll
        for (int n = 0; n < 16; ++n) acc[n] = b2[t];
        for (int k = 0; k < 64; ++k) {
            float w2 = W2[k * C3 + t];
            #pragma unroll
            for (int n = 0; n < 16; ++n) acc[n] += hs[n][k] * w2;
        }
        #pragma unroll
        for (int n = 0; n < 16; ++n) x_h[(size_t)(base + n) * C3 + t] = acc[n];
    }
}

// ---------------------------------------------------------------------------
// CSR build: histogram -> offset scan -> scatter  (no group tables anymore)
// ---------------------------------------------------------------------------
__global__ void hist_k(const int* __restrict__ eidx, int* __restrict__ counts) {
    int e = blockIdx.x * 256 + threadIdx.x;
    if (e < N_EDGES) atomicAdd(&counts[eidx[N_EDGES + e]], 1);
}

__global__ __launch_bounds__(1024)
void scan_k(const int* __restrict__ counts, int* __restrict__ first_edge) {
    __shared__ int ls[1024];
    const int t = threadIdx.x;
    const int CH = 49;                 // 1024*49 = 50176 >= 50000
    const int base = t * CH;
    int s = 0;
    for (int k = 0; k < CH; ++k) {
        int i = base + k;
        if (i < N_NODES) s += counts[i];
    }
    ls[t] = s;
    __syncthreads();
    for (int off = 1; off < 1024; off <<= 1) {   // Hillis-Steele inclusive
        int v = (t >= off) ? ls[t - off] : 0;
        __syncthreads();
        ls[t] += v;
        __syncthreads();
    }
    int run = (t == 0) ? 0 : ls[t - 1];
    for (int k = 0; k < CH; ++k) {
        int i = base + k;
        if (i < N_NODES) {
            first_edge[i] = run;
            run += counts[i];
        }
    }
}

__global__ void scatter_k(const int* __restrict__ eidx,
                          const int* __restrict__ first_edge,
                          int* __restrict__ cursor, int* __restrict__ perm) {
    int e = blockIdx.x * 256 + threadIdx.x;
    if (e >= N_EDGES) return;
    int i = eidx[N_EDGES + e];
    int pos = atomicAdd(&cursor[i], 1);
    perm[first_edge[i] + pos] = e;
}

// ---------------------------------------------------------------------------
// Fused edge kernel: ONE WAVE PER NODE. The wave loops over ceil(d/16)
// batches of 16 destination-sorted edges, accumulating the quad-reduced
// 16-edge partial sums in 8 registers. Output row is written ONCE with
// plain coalesced stores -> zero atomics (was 37.6M fp32 RMWs), and the
// d_out memset is gone (degree-0 nodes store zeros).
// Per-wave LDS staging (no __syncthreads in this kernel at all).
// ---------------------------------------------------------------------------
__global__ __launch_bounds__(256)
void edge_kernel(const float* __restrict__ edge_rbf,
                 const __bf16* __restrict__ WeT,
                 const float* __restrict__ be,
                 const float* __restrict__ x_h,
                 const float* __restrict__ vec,
                 const float* __restrict__ edge_vector,
                 const int*   __restrict__ eidx,
                 const int*   __restrict__ perm,
                 const int*   __restrict__ counts,
                 const int*   __restrict__ first_edge,
                 float* __restrict__ d_x, float* __restrict__ d_vec) {
    __shared__ __bf16 Ash[4][16][136];   // per-wave region; pad 8 -> free 2-way
    const int t = threadIdx.x;
    const int w = t >> 6, l = t & 63;
    const int er = l & 15, quad = l >> 4;
    const int i_node = blockIdx.x * 4 + w;

    const int d   = counts[i_node];
    const int off = first_edge[i_node];

    // acc[h] holds ct = quad + 4*h  (h=0,1): [d_x, dv0, dv1, dv2] slices
    float aX0 = 0.f, aX1 = 0.f;
    float a10 = 0.f, a11 = 0.f;
    float a20 = 0.f, a21 = 0.f;
    float a30 = 0.f, a31 = 0.f;

    if (d > 0) {
        const int e0 = perm[off];          // valid padding edge (masked later)
        const int nb = (d + 15) >> 4;
        for (int b = 0; b < nb; ++b) {
            const int sbase = b * 16;
            // ---- stage 16 gathered rbf rows f32 -> bf16 (wave-local) ----
            #pragma unroll
            for (int it = 0; it < 8; ++it) {
                int fidx = it * 64 + l;        // 512 float4 / 16 rows
                int row  = fidx >> 5;
                int c4   = fidx & 31;
                int slot = sbase + row;
                int e    = (slot < d) ? perm[off + slot] : e0;
                const float4 v = *(const float4*)(edge_rbf + (size_t)e * NF + c4 * 4);
                bf16x4 bb;
                bb[0] = (__bf16)v.x; bb[1] = (__bf16)v.y;
                bb[2] = (__bf16)v.z; bb[3] = (__bf16)v.w;
                *(bf16x4*)&Ash[w][row][c4 * 4] = bb;
            }
            // wave-local LDS RAW: compiler inserts lgkmcnt wait (no barrier)
            bf16x8 afrag[4];
            #pragma unroll
            for (int s = 0; s < 4; ++s)
                afrag[s] = *(const bf16x8*)&Ash[w][er][s * 32 + quad * 8];

            // per-(quad,r) edge scalars
            int jj[4]; float ev0[4], ev1[4], ev2[4]; int vld[4];
            #pragma unroll
            for (int r = 0; r < 4; ++r) {
                int slot = sbase + quad * 4 + r;
                int e    = (slot < d) ? perm[off + slot] : e0;
                vld[r]   = (slot < d);
                jj[r]    = eidx[e];
                ev0[r]   = edge_vector[(size_t)e * 3 + 0];
                ev1[r]   = edge_vector[(size_t)e * 3 + 1];
                ev2[r]   = edge_vector[(size_t)e * 3 + 2];
            }

            #pragma unroll
            for (int ct = 0; ct < 8; ++ct) {
                floatx4 a1 = (floatx4){0.f,0.f,0.f,0.f};
                floatx4 a2 = (floatx4){0.f,0.f,0.f,0.f};
                floatx4 a3 = (floatx4){0.f,0.f,0.f,0.f};
                #pragma unroll
                for (int s = 0; s < 4; ++s) {
                    const __bf16* bb = WeT + (size_t)(16 * ct + er) * NF + s * 32 + quad * 8;
                    a1 = __builtin_amdgcn_mfma_f32_16x16x32_bf16(afrag[s], *(const bf16x8*)bb, a1, 0, 0, 0);
                    a2 = __builtin_amdgcn_mfma_f32_16x16x32_bf16(afrag[s], *(const bf16x8*)(bb + 128 * NF), a2, 0, 0, 0);
                    a3 = __builtin_amdgcn_mfma_f32_16x16x32_bf16(afrag[s], *(const bf16x8*)(bb + 256 * NF), a3, 0, 0, 0);
                }
                const int cc = ct * 16 + er;
                const float be1 = be[cc], be2 = be[cc + 128], be3 = be[cc + 256];
                float p0 = 0.f, p1 = 0.f, p2 = 0.f, p3 = 0.f;
                #pragma unroll
                for (int r = 0; r < 4; ++r) {
                    const float* xh = x_h + (size_t)jj[r] * C3;
                    const float* vj = vec + (size_t)jj[r] * 3 * HID;
                    float rbf1 = a1[r] + be1;
                    float rbf2 = a2[r] + be2;
                    float rbf3 = a3[r] + be3;
                    float x1 = xh[cc]       * rbf1 * INV_SQRT3;
                    float x2 = xh[cc + 128] * rbf2 * INV_SQRT3;
                    float x3 = xh[cc + 256] * rbf3 * INV_SQRT3;
                    if (!vld[r]) { x1 = 0.f; x2 = 0.f; x3 = 0.f; }
                    p0 += x3;
                    p1 += x1 * vj[cc]       + x2 * ev0[r];
                    p2 += x1 * vj[cc + 128] + x2 * ev1[r];
                    p3 += x1 * vj[cc + 256] + x2 * ev2[r];
                }
                // reduce the 16 edges of this batch across quads
                p0 += __shfl_xor(p0, 16, 64); p0 += __shfl_xor(p0, 32, 64);
                p1 += __shfl_xor(p1, 16, 64); p1 += __shfl_xor(p1, 32, 64);
                p2 += __shfl_xor(p2, 16, 64); p2 += __shfl_xor(p2, 32, 64);
                p3 += __shfl_xor(p3, 16, 64); p3 += __shfl_xor(p3, 32, 64);
                if ((ct & 3) == quad) {      // this lane owns ct = quad + 4h
                    if ((ct >> 2) == 0) { aX0 += p0; a10 += p1; a20 += p2; a30 += p3; }
                    else                { aX1 += p0; a11 += p1; a21 += p2; a31 += p3; }
                }
            }
        }
    }

    // ---- single coalesced row store (covers degree-0 nodes with zeros) ----
    float* dxp = d_x  + (size_t)i_node * HID;
    float* dvp = d_vec + (size_t)i_node * 3 * HID;
    // lane l holds cc=l (h=0) and cc=64+l (h=1)
    dxp[l]        = aX0;
    dxp[64 + l]   = aX1;
    dvp[l]        = a10 * INV_SQRTH;
    dvp[64 + l]   = a11 * INV_SQRTH;
    dvp[128 + l]  = a20 * INV_SQRTH;
    dvp[192 + l]  = a21 * INV_SQRTH;
    dvp[256 + l]  = a30 * INV_SQRTH;
    dvp[320 + l]  = a31 * INV_SQRTH;
}

// ---------------------------------------------------------------------------
extern "C" void kernel_launch(void* const* d_in, const int* in_sizes, int n_in,
                              void* d_out, int out_size, void* d_ws, size_t ws_size,
                              hipStream_t stream) {
    const float* x    = (const float*)d_in[0];
    const float* vec  = (const float*)d_in[1];
    const float* erbf = (const float*)d_in[2];
    const float* evec = (const float*)d_in[3];
    const int*   eidx = (const int*)d_in[4];
    const float* W1   = (const float*)d_in[5];
    const float* b1   = (const float*)d_in[6];
    const float* W2   = (const float*)d_in[7];
    const float* b2   = (const float*)d_in[8];
    const float* We   = (const float*)d_in[9];
    const float* be   = (const float*)d_in[10];

    float* out   = (float*)d_out;
    float* d_x   = out;                              // [N, H]
    float* d_vec = out + (size_t)N_NODES * HID;      // [N, 3, H]

    // ---- workspace layout (all 256B-aligned) ----
    char* p = (char*)d_ws;
    float*  x_h        = (float*)p;  p += (size_t)N_NODES * C3 * 4;     // 76.8 MB
    __bf16* WeT        = (__bf16*)p; p += (size_t)C3 * NF * 2;          // 96 KB
    int* first_edge    = (int*)p;    p += 50176 * 4;
    int* perm          = (int*)p;    p += (size_t)N_EDGES * 4;          // 3.2 MB
    // zero-initialized region: counts, cursor (one small memset)
    char* zbase        = p;
    int* counts        = (int*)p;    p += 50176 * 4;
    int* cursor        = (int*)p;    p += 50176 * 4;
    size_t zbytes      = (size_t)(p - zbase);

    hipMemsetAsync(zbase, 0, zbytes, stream);
    // NOTE: no d_out memset needed — edge_kernel stores every output element.

    cast_weT<<<(C3 * NF) / 256, 256, 0, stream>>>(We, WeT);
    node_mlp<<<N_NODES / 16, 384, 0, stream>>>(x, W1, b1, W2, b2, x_h);
    hist_k<<<(N_EDGES + 255) / 256, 256, 0, stream>>>(eidx, counts);
    scan_k<<<1, 1024, 0, stream>>>(counts, first_edge);
    scatter_k<<<(N_EDGES + 255) / 256, 256, 0, stream>>>(eidx, first_edge, cursor, perm);
    edge_kernel<<<N_NODES / 4, 256, 0, stream>>>(erbf, WeT, be, x_h, vec, evec, eidx,
                                                 perm, counts, first_edge,
                                                 d_x, d_vec);
}